// Round 3
// baseline (272.933 us; speedup 1.0000x reference)
//
#include <hip/hip_runtime.h>

#define NB 8
#define CCH 256
#define DQK 32
#define NPIX 4096

typedef __attribute__((ext_vector_type(8))) short short8;
typedef __attribute__((ext_vector_type(4))) float f32x4;
typedef __attribute__((ext_vector_type(4))) unsigned short ushort4v;

static __device__ __forceinline__ unsigned short f2bf(float f) {
  unsigned int u = __builtin_bit_cast(unsigned int, f);
  u += 0x7FFFu + ((u >> 16) & 1u);
  return (unsigned short)(u >> 16);
}
static __device__ __forceinline__ unsigned int pack2bf(float a, float b) {
  return (unsigned int)f2bf(a) | ((unsigned int)f2bf(b) << 16);
}

// ---------------- kernel 0: convert W (320x256 fp32, rows Q|K|V) to bf16 ----------------
__global__ __launch_bounds__(256) void wconv_kernel(
    const float* __restrict__ Wq, const float* __restrict__ Wk,
    const float* __restrict__ Wv, unsigned short* __restrict__ Wbf) {
  const int e = (blockIdx.x * 256 + threadIdx.x) * 4;
  const int m = e >> 8, c = e & 255;
  const float* src;
  if (m < 32) src = Wq + (size_t)m * CCH;
  else if (m < 64) src = Wk + (size_t)(m - 32) * CCH;
  else src = Wv + (size_t)(m - 64) * CCH;
  const float4 v = *(const float4*)(src + c);
  ushort4v o;
  o[0] = f2bf(v.x); o[1] = f2bf(v.y); o[2] = f2bf(v.z); o[3] = f2bf(v.w);
  *(ushort4v*)(Wbf + e) = o;
}

// ---------------- projection: q,k,v = W x + b (bf16 out) ----------------
// grid 1024; b = bid&7 (XCD-aligned), px-tile = 32. 4 blocks/CU.
__global__ __launch_bounds__(256) void proj_kernel(
    const float* __restrict__ x, const unsigned short* __restrict__ Wbf,
    const float* __restrict__ bq, const float* __restrict__ bk,
    const float* __restrict__ bv,
    unsigned short* __restrict__ Qb, unsigned short* __restrict__ Kb,
    unsigned short* __restrict__ Vb) {
  __shared__ unsigned short xs[32 * 256];  // [px][c] swizzled, 16 KB
  const int t = threadIdx.x;
  const int b = blockIdx.x & 7;
  const int i0 = (blockIdx.x >> 3) * 32;
  const float* xb = x + (size_t)b * CCH * NPIX + i0;
  {
    const int ii = (t & 7) * 4;
    const int cb = t >> 3;
    const int sw8 = ((ii >> 2) & 7) << 3;
#pragma unroll
    for (int rep = 0; rep < 8; ++rep) {
      const int c = cb + 32 * rep;
      const float4 v = *(const float4*)(xb + (size_t)c * NPIX + ii);
      const float vv[4] = {v.x, v.y, v.z, v.w};
#pragma unroll
      for (int d = 0; d < 4; ++d) {
        const int cc = (c ^ sw8) ^ ((d & 1) << 4);
        xs[(ii + d) * 256 + cc] = f2bf(vv[d]);
      }
    }
  }
  __syncthreads();
  const int w = t >> 6, l = t & 63;
  const int lc = l & 15, lg = l >> 4;
  const int m0w = 80 * w;
  f32x4 acc[5][2];
#pragma unroll
  for (int mt = 0; mt < 5; ++mt)
#pragma unroll
    for (int nt = 0; nt < 2; ++nt) acc[mt][nt] = (f32x4){0.f, 0.f, 0.f, 0.f};

#pragma unroll
  for (int kk = 0; kk < 8; ++kk) {
    short8 af[5];
#pragma unroll
    for (int mt = 0; mt < 5; ++mt)
      af[mt] = *(const short8*)(Wbf + (size_t)(m0w + mt * 16 + lc) * CCH + kk * 32 + lg * 8);
#pragma unroll
    for (int nt = 0; nt < 2; ++nt) {
      const int i = nt * 16 + lc;
      const int s = (4 * nt + (lc >> 2)) & 7;
      const int cc = ((kk * 32 + lg * 8) ^ (s << 3)) ^ ((lc & 1) << 4);
      const short8 bfv = *(const short8*)&xs[i * 256 + cc];
#pragma unroll
      for (int mt = 0; mt < 5; ++mt)
        acc[mt][nt] = __builtin_amdgcn_mfma_f32_16x16x32_bf16(af[mt], bfv, acc[mt][nt], 0, 0, 0);
    }
  }
#pragma unroll
  for (int mt = 0; mt < 5; ++mt) {
    const int mbase = m0w + mt * 16;
    const int mrow = mbase + 4 * lg;
    if (mbase < 64) {  // Q or K rows (wave 0 only)
      const float* bias = (mbase < 32) ? (bq + mrow) : (bk + (mrow - 32));
      unsigned short* dst = (mbase < 32) ? (Qb + (size_t)b * NPIX * DQK + mrow)
                                         : (Kb + (size_t)b * NPIX * DQK + (mrow - 32));
      const float b0 = bias[0], b1 = bias[1], b2 = bias[2], b3 = bias[3];
#pragma unroll
      for (int nt = 0; nt < 2; ++nt) {
        const int i = i0 + nt * 16 + lc;
        ushort4v o;
        o[0] = f2bf(acc[mt][nt][0] + b0);
        o[1] = f2bf(acc[mt][nt][1] + b1);
        o[2] = f2bf(acc[mt][nt][2] + b2);
        o[3] = f2bf(acc[mt][nt][3] + b3);
        *(ushort4v*)(dst + (size_t)i * DQK) = o;
      }
    } else {  // V rows, (C,N) layout
      const int vrow = mbase - 64 + 4 * lg;
#pragma unroll
      for (int jj = 0; jj < 4; ++jj) {
        const float bias = bv[vrow + jj];
        unsigned short* vdst = Vb + ((size_t)b * CCH + vrow + jj) * NPIX + i0;
#pragma unroll
        for (int nt = 0; nt < 2; ++nt)
          vdst[nt * 16 + lc] = f2bf(acc[mt][nt][jj] + bias);
      }
    }
  }
}

// ---------------- fused attention ----------------
// grid 512; b = bid&7 (XCD-aligned -> per-XCD L2 holds batch's K/V/Q).
// Swapped QK (S rows = keys in regs), double-buffered P in LDS, ONE barrier/tile,
// V[t+1]/K[t+2] register-prefetched across the barrier. No-max softmax.
union AttnSmem {
  unsigned short p[2][64 * 64];  // 16 KB, [q][key] swizzled
  float tsc[4][16 * 68];         // 17.4 KB epilogue transpose
};

__global__ __launch_bounds__(256, 2) void attn_kernel(
    const unsigned short* __restrict__ Qb,
    const unsigned short* __restrict__ Kb,
    const unsigned short* __restrict__ Vb,
    const float* __restrict__ x,
    const float* __restrict__ gammap,
    float* __restrict__ out) {
  __shared__ AttnSmem sm;
  __shared__ float l_lds[64];
  const int t = threadIdx.x;
  const int w = t >> 6, l = t & 63;
  const int lc = l & 15, lg = l >> 4;
  const int b = blockIdx.x & 7;
  const int q0 = (blockIdx.x >> 3) * 64;

  const unsigned short* Kl = Kb + (size_t)b * NPIX * DQK + (size_t)lc * DQK + lg * 8;
  const unsigned short* Vl = Vb + ((size_t)b * CCH + 64 * w + lc) * NPIX + lg * 8;
  const short8 qa = *(const short8*)(Qb + (size_t)b * NPIX * DQK +
                                     (size_t)(q0 + 16 * w + lc) * DQK + lg * 8);
  const f32x4 zero4 = {0.f, 0.f, 0.f, 0.f};
  const int pwb = (16 * w + lc) * 128;  // P-write row base (bytes)
  const int psw = (lc & 7) << 3;        // element swizzle mask

  f32x4 acc[4][4];
#pragma unroll
  for (int mt = 0; mt < 4; ++mt)
#pragma unroll
    for (int ct = 0; ct < 4; ++ct) acc[mt][ct] = (f32x4){0.f, 0.f, 0.f, 0.f};
  float psum = 0.f;

  short8 vfA[8], vfB[8], kfA[4], kfB[4];

  // prologue: S/P for tile 0 -> buf 0; prefetch V[0] -> vfA, K[1] -> kfB
#pragma unroll
  for (int kt = 0; kt < 4; ++kt)
    kfA[kt] = *(const short8*)(Kl + (size_t)(kt * 16) * DQK);
#pragma unroll
  for (int kt = 0; kt < 4; ++kt) {
    const f32x4 s = __builtin_amdgcn_mfma_f32_16x16x32_bf16(kfA[kt], qa, zero4, 0, 0, 0);
    const float p0 = __expf(s[0]), p1 = __expf(s[1]);
    const float p2 = __expf(s[2]), p3 = __expf(s[3]);
    psum += (p0 + p1) + (p2 + p3);
    uint2 wv; wv.x = pack2bf(p0, p1); wv.y = pack2bf(p2, p3);
    *(uint2*)((char*)sm.p[0] + pwb + (((16 * kt + 4 * lg) ^ psw) << 1)) = wv;
  }
#pragma unroll
  for (int ct = 0; ct < 4; ++ct) {
    vfA[ct] = *(const short8*)(Vl + (size_t)(16 * ct) * NPIX);
    vfA[4 + ct] = *(const short8*)(Vl + (size_t)(16 * ct) * NPIX + 32);
  }
#pragma unroll
  for (int kt = 0; kt < 4; ++kt)
    kfB[kt] = *(const short8*)(Kl + (size_t)(64 + kt * 16) * DQK);
  __syncthreads();

#define ATTN_ITER(T, BUF, VF, KF_CUR, VF_NXT, KF_NXT)                               \
  {                                                                                 \
    const int t_ = (T);                                                             \
    if (t_ < 63) {                                                                  \
      const size_t kb2 = (size_t)(t_ + 1) * 64;                                     \
      _Pragma("unroll") for (int ct = 0; ct < 4; ++ct) {                            \
        VF_NXT[ct] = *(const short8*)(Vl + (size_t)(16 * ct) * NPIX + kb2);         \
        VF_NXT[4 + ct] = *(const short8*)(Vl + (size_t)(16 * ct) * NPIX + kb2 + 32);\
      }                                                                             \
      if (t_ < 62) {                                                                \
        const size_t kk2 = (size_t)(t_ + 2) * 64;                                   \
        _Pragma("unroll") for (int kt = 0; kt < 4; ++kt)                            \
          KF_NXT[kt] = *(const short8*)(Kl + (kk2 + kt * 16) * DQK);                \
      }                                                                             \
    }                                                                               \
    unsigned short* pb_ = sm.p[BUF];                                                \
    unsigned short* pb2_ = sm.p[(BUF) ^ 1];                                         \
    _Pragma("unroll") for (int ks2 = 0; ks2 < 2; ++ks2) {                           \
      short8 pa[4];                                                                 \
      _Pragma("unroll") for (int mt = 0; mt < 4; ++mt)                              \
        pa[mt] = *(const short8*)((const char*)pb_ + (16 * mt + lc) * 128 +         \
                                  (((32 * ks2 + 8 * lg) ^ psw) << 1));              \
      _Pragma("unroll") for (int ct = 0; ct < 4; ++ct)                              \
        _Pragma("unroll") for (int mt = 0; mt < 4; ++mt)                            \
          acc[mt][ct] = __builtin_amdgcn_mfma_f32_16x16x32_bf16(                    \
              pa[mt], VF[ks2 * 4 + ct], acc[mt][ct], 0, 0, 0);                      \
    }                                                                               \
    if (t_ < 63) {                                                                  \
      _Pragma("unroll") for (int kt = 0; kt < 4; ++kt) {                            \
        const f32x4 s = __builtin_amdgcn_mfma_f32_16x16x32_bf16(                    \
            KF_CUR[kt], qa, zero4, 0, 0, 0);                                        \
        const float p0 = __expf(s[0]), p1 = __expf(s[1]);                           \
        const float p2 = __expf(s[2]), p3 = __expf(s[3]);                           \
        psum += (p0 + p1) + (p2 + p3);                                              \
        uint2 wv; wv.x = pack2bf(p0, p1); wv.y = pack2bf(p2, p3);                   \
        *(uint2*)((char*)pb2_ + pwb + (((16 * kt + 4 * lg) ^ psw) << 1)) = wv;      \
      }                                                                             \
    }                                                                               \
    __syncthreads();                                                                \
  }

  for (int ks = 0; ks < 64; ks += 2) {
    ATTN_ITER(ks, 0, vfA, kfB, vfB, kfA);
    ATTN_ITER(ks + 1, 1, vfB, kfA, vfA, kfB);
  }
#undef ATTN_ITER

  // l reduction across the 4 lane-groups (each lane summed its 16 keys/tile)
  {
    float v = psum;
    v += __shfl_xor(v, 16);
    v += __shfl_xor(v, 32);
    if (l < 16) l_lds[16 * w + lc] = v;
  }
  __syncthreads();

  const float g = gammap[0];
  float linv4[4][4];
#pragma unroll
  for (int mt = 0; mt < 4; ++mt)
#pragma unroll
    for (int jj = 0; jj < 4; ++jj)
      linv4[mt][jj] = 1.0f / l_lds[16 * mt + 4 * lg + jj];

  float* tw = sm.tsc[w];
  const float* xbp = x + (size_t)b * CCH * NPIX;
  float* ob = out + (size_t)b * CCH * NPIX;
#pragma unroll
  for (int ct = 0; ct < 4; ++ct) {
#pragma unroll
    for (int mt = 0; mt < 4; ++mt) {
      f32x4 o;
#pragma unroll
      for (int jj = 0; jj < 4; ++jj) o[jj] = g * acc[mt][ct][jj] * linv4[mt][jj];
      *(f32x4*)(tw + lc * 68 + 16 * mt + 4 * lg) = o;  // [c-local][q-local]
    }
    // per-wave in-order DS pipe: RAW within wave handled by lgkmcnt
#pragma unroll
    for (int r = 0; r < 4; ++r) {
      const int crow = 4 * r + lg;
      const f32x4 o = *(const f32x4*)(tw + crow * 68 + lc * 4);
      const size_t idx = (size_t)(64 * w + 16 * ct + crow) * NPIX + (size_t)(q0 + lc * 4);
      const float4 xv = *(const float4*)(xbp + idx);
      float4 ov;
      ov.x = o[0] + xv.x; ov.y = o[1] + xv.y; ov.z = o[2] + xv.z; ov.w = o[3] + xv.w;
      *(float4*)(ob + idx) = ov;
    }
  }
}

extern "C" void kernel_launch(void* const* d_in, const int* in_sizes, int n_in,
                              void* d_out, int out_size, void* d_ws, size_t ws_size,
                              hipStream_t stream) {
  (void)in_sizes; (void)n_in; (void)out_size; (void)ws_size;
  const float* x     = (const float*)d_in[0];
  const float* Wq    = (const float*)d_in[1];
  const float* bq    = (const float*)d_in[2];
  const float* Wk    = (const float*)d_in[3];
  const float* bk    = (const float*)d_in[4];
  const float* Wv    = (const float*)d_in[5];
  const float* bv    = (const float*)d_in[6];
  const float* gamma = (const float*)d_in[7];

  unsigned short* Wbf = (unsigned short*)d_ws;            // 160 KB
  unsigned short* Qb  = Wbf + 320 * CCH;                  // 2 MB
  unsigned short* Kb  = Qb + (size_t)NB * NPIX * DQK;     // 2 MB
  unsigned short* Vb  = Kb + (size_t)NB * NPIX * DQK;     // 16 MB

  wconv_kernel<<<80, 256, 0, stream>>>(Wq, Wk, Wv, Wbf);
  proj_kernel<<<1024, 256, 0, stream>>>(x, Wbf, bq, bk, bv, Qb, Kb, Vb);
  attn_kernel<<<512, 256, 0, stream>>>(Qb, Kb, Vb, x, gamma, (float*)d_out);
}